// Round 1
// baseline (206.833 us; speedup 1.0000x reference)
//
#include <hip/hip_runtime.h>
#include <hip/hip_bf16.h>

// EMD loss: out[r] = sum_j ( cumsum(x[r]-y[r])[j] )^2, rows=1048576, bins=128, fp32.
// Memory-bound streaming: 1 GB read, 4 MB write. One wave = 2 rows
// (32 lanes/row, float4 = 4 bins per lane).

constexpr int BINS = 128;
constexpr int F4_PER_ROW = BINS / 4;  // 32

__global__ __launch_bounds__(256) void emd_kernel(
    const float4* __restrict__ x4, const float4* __restrict__ y4,
    float* __restrict__ out, int nrows) {
    const int tid     = blockIdx.x * blockDim.x + threadIdx.x;
    const int lane    = threadIdx.x & 63;
    const int j       = lane & 31;   // float4 index within row
    const int half    = lane >> 5;   // which of the wave's 2 rows
    const int wave    = tid >> 6;
    const int nwaves  = (gridDim.x * blockDim.x) >> 6;
    const int npairs  = nrows >> 1;  // rows handled 2-at-a-time

    for (int pair = wave; pair < npairs; pair += nwaves) {
        const int r = pair * 2 + half;          // nrows is even
        const int base = r * F4_PER_ROW + j;    // < 2^25, fits int
        const float4 xv = x4[base];
        const float4 yv = y4[base];

        // per-lane diffs and local inclusive prefix
        const float d0 = xv.x - yv.x;
        const float d1 = xv.y - yv.y;
        const float d2 = xv.z - yv.z;
        const float d3 = xv.w - yv.w;
        const float p0 = d0;
        const float p1 = p0 + d1;
        const float p2 = p1 + d2;
        const float p3 = p2 + d3;

        // inclusive scan of lane sums across the 32 lanes of this row
        float scan = p3;
        #pragma unroll
        for (int off = 1; off < 32; off <<= 1) {
            const float n = __shfl_up(scan, off, 32);
            if (j >= off) scan += n;
        }
        const float excl = scan - p3;  // exclusive prefix for this lane

        const float c0 = excl + p0;
        const float c1 = excl + p1;
        const float c2 = excl + p2;
        const float c3 = excl + p3;
        float acc = c0 * c0 + c1 * c1 + c2 * c2 + c3 * c3;

        // reduce sum-of-squares across the 32 lanes of this row
        #pragma unroll
        for (int off = 16; off > 0; off >>= 1)
            acc += __shfl_down(acc, off, 32);

        if (j == 0) out[r] = acc;
    }
}

extern "C" void kernel_launch(void* const* d_in, const int* in_sizes, int n_in,
                              void* d_out, int out_size, void* d_ws, size_t ws_size,
                              hipStream_t stream) {
    const float4* x4 = (const float4*)d_in[0];
    const float4* y4 = (const float4*)d_in[1];
    float* out = (float*)d_out;
    const int nrows = out_size;  // 1048576

    const int block = 256;
    const int grid  = 2048;  // grid-stride; 8192 waves cover 16384 rows/sweep
    emd_kernel<<<grid, block, 0, stream>>>(x4, y4, out, nrows);
}